// Round 1
// baseline (304.252 us; speedup 1.0000x reference)
//
#include <hip/hip_runtime.h>

typedef _Float16 v2h __attribute__((ext_vector_type(2)));
typedef _Float16 v8h __attribute__((ext_vector_type(8)));
typedef float v4f __attribute__((ext_vector_type(4)));

#define EMB 256
#define VOCAB 50000
#define NSTEP 101   // output rows

// ---------------- helpers ----------------
__device__ __forceinline__ float sigf(float x) {
    return 1.f / (1.f + __expf(-x));
}
__device__ __forceinline__ float tanhf_(float x) {
    float e = __expf(2.f * fabsf(x));
    float th = 1.f - 2.f / (e + 1.f);
    return copysignf(th, x);
}
__device__ __forceinline__ float fdot2_(v2h a, v2h b, float c) {
    return __builtin_amdgcn_fdot2(a, b, c, false);
}

// ---------------- K1: conv/BN stack (1 block, 384 threads) ----------------
__global__ __launch_bounds__(384) void k_conv(
        const float* __restrict__ board, const float* __restrict__ conv_w,
        const float* __restrict__ conv_b, const float* __restrict__ gamma,
        const float* __restrict__ beta, const float* __restrict__ p,
        float* __restrict__ d1_out) {
    __shared__ float cur[361];
    __shared__ float red1[8], red2[8];
    __shared__ float stats[2];
    const int t = threadIdx.x;
    const bool act = t < 361;
    const int r = t / 19, c = t % 19;
    float w[9];
#pragma unroll
    for (int k = 0; k < 9; ++k) w[k] = conv_w[k];
    const float cb = conv_b[0], ga = gamma[0], be = beta[0];
    float scales[8] = {p[0], p[1], p[2], p[3], p[4], p[5], p[6], 1.f};
    const int mode[8] = {2, 0, 1, 0, 1, 0, 1, 0}; // 2: set d2; 1: +d2 then set d2; 0: plain
    if (act) cur[t] = board[t];
    float d2r = 0.f;
    __syncthreads();
#pragma unroll
    for (int it = 0; it < 8; ++it) {
        float y = 0.f;
        if (act) {
#pragma unroll
            for (int di = 0; di < 3; ++di)
#pragma unroll
                for (int dj = 0; dj < 3; ++dj) {
                    int rr = r + di - 1, cc2 = c + dj - 1;
                    if (rr >= 0 && rr < 19 && cc2 >= 0 && cc2 < 19)
                        y += cur[rr * 19 + cc2] * w[di * 3 + dj];
                }
            y += cb;
        }
        float s1 = y, s2 = y * y;
        for (int m = 32; m; m >>= 1) {
            s1 += __shfl_xor(s1, m);
            s2 += __shfl_xor(s2, m);
        }
        const int wv = t >> 6;
        if ((t & 63) == 0) { red1[wv] = s1; red2[wv] = s2; }
        __syncthreads();
        if (t == 0) {
            float a = 0.f, b2 = 0.f;
            for (int i = 0; i < 6; ++i) { a += red1[i]; b2 += red2[i]; }
            float mu = a / 361.f;
            float var = b2 / 361.f - mu * mu;
            stats[0] = mu;
            stats[1] = rsqrtf(var + 1e-5f);
        }
        __syncthreads();
        float mu = stats[0], rs = stats[1];
        float v = ga * (y - mu) * rs + be;
        v *= scales[it];
        if (mode[it] == 1) v += d2r;
        v = fmaxf(v, 0.f);
        if (mode[it] != 0) d2r = v;
        if (act) cur[t] = v;
        __syncthreads();
    }
    if (act) d1_out[t] = cur[t];
}

// ---------------- K2: feat + W_sum(f16) + b_sum (81 blocks x 256) ----------------
__global__ __launch_bounds__(256) void k_prep(
        const float* __restrict__ Wlin, const float* __restrict__ blin,
        const float* __restrict__ d1,
        const float* __restrict__ Wih, const float* __restrict__ bih,
        const float* __restrict__ Whh, const float* __restrict__ bhh,
        float* __restrict__ feat, _Float16* __restrict__ wsum,
        float* __restrict__ bsum) {
    const int b = blockIdx.x, t = threadIdx.x;
    if (b < 16) {
        // feat rows: 16 per block, 16 lanes per row (23 k-elems each)
        const int r = b * 16 + (t >> 4), kc = t & 15;
        const int k0 = kc * 23, k1 = (k0 + 23 < 361) ? k0 + 23 : 361;
        const float* wrow = Wlin + r * 361;
        float acc = 0.f;
        for (int k = k0; k < k1; ++k) acc += wrow[k] * d1[k];
        for (int m = 1; m < 16; m <<= 1) acc += __shfl_xor(acc, m);
        if (kc == 0) feat[r] = acc + blin[r];
    } else if (b < 80) {
        const int base = (b - 16) * 4096 + t;
#pragma unroll
        for (int i = 0; i < 16; ++i) {
            int idx = base + i * 256;
            wsum[idx] = (_Float16)(Wih[idx] + Whh[idx]);
        }
    } else {
        for (int i = t; i < 1024; i += 256) bsum[i] = bih[i] + bhh[i];
    }
}

// ---------------- K2b: gates0 = W_ih@feat + b_ih + b_hh (64 blocks x 256) -------
__global__ __launch_bounds__(256) void k_gates0(
        const float* __restrict__ Wih, const float* __restrict__ feat,
        const float* __restrict__ bih, const float* __restrict__ bhh,
        float* __restrict__ gates0) {
    const int r = blockIdx.x * 16 + (threadIdx.x >> 4), kc = threadIdx.x & 15;
    const float* wrow = Wih + r * 256 + kc * 16;
    const float* f = feat + kc * 16;
    float acc = 0.f;
#pragma unroll
    for (int k = 0; k < 16; ++k) acc += wrow[k] * f[k];
    for (int m = 1; m < 16; m <<= 1) acc += __shfl_xor(acc, m);
    if (kc == 0) gates0[r] = acc + bih[r] + bhh[r];
}

// ---------------- K3: 101-step LSTM chain (1 block x 512, weights resident) ----
// Thread t: idx = t&255, half = t>>8. Owns all 4 gate rows {idx+256j} on the
// k-range [half*128, half*128+128). k-elems [0,96) of the range live in VGPRs
// (48 v2h per row), k-elems [96,128) live in LDS (XOR-swizzled, thread-major).
__global__ __launch_bounds__(512, 2) void k_lstm(
        const _Float16* __restrict__ wsum, const float* __restrict__ bsum,
        const float* __restrict__ gates0, _Float16* __restrict__ Hg) {
    extern __shared__ char smem[];
    _Float16* Wl = (_Float16*)smem;                  // 131072 B
    _Float16* hbuf = (_Float16*)(smem + 131072);     // 512 B
    float* part = (float*)(smem + 131584);           // 4096 B
    const int t = threadIdx.x;
    const int idx = t & 255;
    const int half = t >> 8;
    const int kbase = half * 128;
    const int sw = (t & 15) << 4;

    // --- load register-resident weights ---
    v2h wr[4][48];
#pragma unroll
    for (int j = 0; j < 4; ++j) {
        const _Float16* src = wsum + (idx + 256 * j) * 256 + kbase;
#pragma unroll
        for (int q = 0; q < 12; ++q) {
            float4 fv = *(const float4*)(src + q * 8);
            const v2h* vp = (const v2h*)&fv;
            wr[j][q * 4 + 0] = vp[0];
            wr[j][q * 4 + 1] = vp[1];
            wr[j][q * 4 + 2] = vp[2];
            wr[j][q * 4 + 3] = vp[3];
        }
    }
    // --- stage LDS-resident weights (thread-major, 16B-slot XOR swizzle) ---
#pragma unroll
    for (int j = 0; j < 4; ++j) {
        const _Float16* src = wsum + (idx + 256 * j) * 256 + kbase + 96;
#pragma unroll
        for (int cc = 0; cc < 4; ++cc) {
            float4 fv = *(const float4*)(src + cc * 8);
            const int c = j * 4 + cc;
            *(float4*)((char*)Wl + t * 256 + ((c * 16) ^ sw)) = fv;
        }
    }
    const float bs0 = bsum[idx], bs1 = bsum[idx + 256];
    const float bs2 = bsum[idx + 512], bs3 = bsum[idx + 768];
    float cst = 0.f;
    // --- step 0: cell(feat, 0, 0) from precomputed gates0 ---
    if (half == 0) {
        float gi = gates0[idx], gg = gates0[idx + 512], go = gates0[idx + 768];
        cst = sigf(gi) * tanhf_(gg);      // f-gate * c(=0) drops out
        float h = sigf(go) * tanhf_(cst);
        hbuf[idx] = (_Float16)h;
        Hg[idx] = (_Float16)h;
    }
    __syncthreads();

    for (int step = 1; step <= 100; ++step) {
        float acc[4];
        acc[0] = 0.f; acc[1] = 0.f; acc[2] = 0.f; acc[3] = 0.f;
        const v2h* hp = ((const v2h*)hbuf) + half * 64;
        // register-weight MACs: k in [kbase, kbase+96)
#pragma unroll
        for (int q = 0; q < 12; ++q) {
            float4 hv = *(const float4*)(hp + q * 4);
            const v2h* h4 = (const v2h*)&hv;
#pragma unroll
            for (int j = 0; j < 4; ++j) {
#pragma unroll
                for (int u = 0; u < 4; ++u)
                    acc[j] = fdot2_(wr[j][q * 4 + u], h4[u], acc[j]);
            }
        }
        // LDS-weight MACs: k in [kbase+96, kbase+128)
#pragma unroll
        for (int cc = 0; cc < 4; ++cc) {
            float4 hv = *(const float4*)(hp + 48 + cc * 4);
            const v2h* h4 = (const v2h*)&hv;
#pragma unroll
            for (int j = 0; j < 4; ++j) {
                const int c = j * 4 + cc;
                float4 wv = *(const float4*)((const char*)Wl + t * 256 + ((c * 16) ^ sw));
                const v2h* w4 = (const v2h*)&wv;
#pragma unroll
                for (int u = 0; u < 4; ++u)
                    acc[j] = fdot2_(w4[u], h4[u], acc[j]);
            }
        }
        if (half == 1) {
            part[0 * 256 + idx] = acc[0];
            part[1 * 256 + idx] = acc[1];
            part[2 * 256 + idx] = acc[2];
            part[3 * 256 + idx] = acc[3];
        }
        __syncthreads();
        if (half == 0) {
            float gi = acc[0] + part[0 * 256 + idx] + bs0;
            float gf = acc[1] + part[1 * 256 + idx] + bs1;
            float gg = acc[2] + part[2 * 256 + idx] + bs2;
            float go = acc[3] + part[3 * 256 + idx] + bs3;
            cst = sigf(gf) * cst + sigf(gi) * tanhf_(gg);
            float h = sigf(go) * tanhf_(cst);
            hbuf[idx] = (_Float16)h;
            Hg[step * 256 + idx] = (_Float16)h;
        }
        __syncthreads();
    }
}

// ---------------- K4: logits GEMM [50048x256]x[256x112] via MFMA f16 ----------
__global__ __launch_bounds__(256) void k_gemm(
        const float* __restrict__ Wdec, const float* __restrict__ bdec,
        const _Float16* __restrict__ Hg, float* __restrict__ out) {
    __shared__ _Float16 Hl[112 * 264];   // padded stride 264 f16 (=528B)
    const int t = threadIdx.x;
    // zero-fill (covers the N-pad rows 101..111 and k-pad)
    float4 z; z.x = 0.f; z.y = 0.f; z.z = 0.f; z.w = 0.f;
    for (int i = t; i < 3696; i += 256) ((float4*)Hl)[i] = z;
    __syncthreads();
    // stage H (101 rows x 256 f16)
    for (int i = t; i < 101 * 32; i += 256) {
        int row = i >> 5, kc = i & 31;
        float4 v = ((const float4*)Hg)[i];
        *(float4*)(Hl + row * 264 + kc * 8) = v;
    }
    __syncthreads();

    const int l = t & 63, wv = t >> 6;
    const int mrow = blockIdx.x * 64 + wv * 16 + (l & 15);
    const int mcl = (mrow < VOCAB) ? mrow : (VOCAB - 1);
    const float* arow = Wdec + (size_t)mcl * 256 + ((l >> 4) << 3);
    const _Float16* brow = Hl + (l & 15) * 264 + ((l >> 4) << 3);

    v4f acc[7];
#pragma unroll
    for (int nt = 0; nt < 7; ++nt) {
#pragma unroll
        for (int j = 0; j < 4; ++j) acc[nt][j] = 0.f;
    }
#pragma unroll
    for (int ks = 0; ks < 8; ++ks) {
        float4 a0 = *(const float4*)(arow + ks * 32);
        float4 a1 = *(const float4*)(arow + ks * 32 + 4);
        v8h af;
        af[0] = (_Float16)a0.x; af[1] = (_Float16)a0.y;
        af[2] = (_Float16)a0.z; af[3] = (_Float16)a0.w;
        af[4] = (_Float16)a1.x; af[5] = (_Float16)a1.y;
        af[6] = (_Float16)a1.z; af[7] = (_Float16)a1.w;
#pragma unroll
        for (int nt = 0; nt < 7; ++nt) {
            v8h bf = *(const v8h*)(brow + nt * 16 * 264 + ks * 32);
            acc[nt] = __builtin_amdgcn_mfma_f32_16x16x32_f16(af, bf, acc[nt], 0, 0, 0);
        }
    }
    const int rowq = blockIdx.x * 64 + wv * 16 + ((l >> 4) << 2);
    if (rowq < VOCAB) {
        float4 bd = *(const float4*)(bdec + rowq);
#pragma unroll
        for (int nt = 0; nt < 7; ++nt) {
            int tt = nt * 16 + (l & 15);
            if (tt <= 100) {
                float4 v;
                v.x = fmaxf(acc[nt][0] + bd.x, 0.f);
                v.y = fmaxf(acc[nt][1] + bd.y, 0.f);
                v.z = fmaxf(acc[nt][2] + bd.z, 0.f);
                v.w = fmaxf(acc[nt][3] + bd.w, 0.f);
                *(float4*)(out + (size_t)tt * VOCAB + rowq) = v;
            }
        }
    }
}

// ---------------- launch ----------------
extern "C" void kernel_launch(void* const* d_in, const int* in_sizes, int n_in,
                              void* d_out, int out_size, void* d_ws, size_t ws_size,
                              hipStream_t stream) {
    const float* board  = (const float*)d_in[0];
    const float* conv_w = (const float*)d_in[1];
    const float* conv_b = (const float*)d_in[2];
    const float* bn_g   = (const float*)d_in[3];
    const float* bn_b   = (const float*)d_in[4];
    const float* p      = (const float*)d_in[5];
    const float* Wlin   = (const float*)d_in[6];
    const float* blin   = (const float*)d_in[7];
    const float* Wih    = (const float*)d_in[8];
    const float* bih    = (const float*)d_in[9];
    const float* Whh    = (const float*)d_in[10];
    const float* bhh    = (const float*)d_in[11];
    const float* Wdec   = (const float*)d_in[12];
    const float* bdec   = (const float*)d_in[13];
    float* out = (float*)d_out;
    char* ws = (char*)d_ws;

    _Float16* wsum  = (_Float16*)(ws);             // 524288 B
    _Float16* Hg    = (_Float16*)(ws + 524288);    // 51712 B
    float* d1       = (float*)(ws + 576512);       // 1444 B
    float* feat     = (float*)(ws + 578560);       // 1024 B
    float* gates0   = (float*)(ws + 579584);       // 4096 B
    float* bsum     = (float*)(ws + 583680);       // 4096 B

    k_conv<<<1, 384, 0, stream>>>(board, conv_w, conv_b, bn_g, bn_b, p, d1);
    k_prep<<<81, 256, 0, stream>>>(Wlin, blin, d1, Wih, bih, Whh, bhh, feat, wsum, bsum);
    k_gates0<<<64, 256, 0, stream>>>(Wih, feat, bih, bhh, gates0);
    k_lstm<<<1, 512, 135680, stream>>>(wsum, bsum, gates0, Hg);
    k_gemm<<<782, 256, 0, stream>>>(Wdec, bdec, Hg, out);
}